// Round 1
// 1045.227 us; speedup vs baseline: 1.1537x; 1.1537x over previous
//
#include <hip/hip_runtime.h>
#include <hip/hip_bf16.h>
#include <math.h>

#define N_NODES 50000
#define N_EDGES 640000
#define DIM 128
#define LDP 136   // padded LDS row length in bf16 elems (row stride 272B -> benign aliasing)

typedef __attribute__((ext_vector_type(8))) short short8;
typedef __attribute__((ext_vector_type(4))) float floatx4;

__device__ __forceinline__ unsigned short f2bf(float f) {
    unsigned int u = __float_as_uint(f);
    u += 0x7FFFu + ((u >> 16) & 1u);       // round-to-nearest-even
    return (unsigned short)(u >> 16);
}
__device__ __forceinline__ float bf2f(unsigned short h) {
    return __uint_as_float(((unsigned int)h) << 16);
}

// ===========================================================================
// NEW PATH
// ===========================================================================

// ---- bf16 pre-conversion (bit-identical to old in-kernel f2bf) ------------
__global__ __launch_bounds__(256) void convert_x(
    const float* __restrict__ x, unsigned short* __restrict__ xb)
{
    size_t i = (size_t)(blockIdx.x * 256 + threadIdx.x) * 8;   // grid 3125
    float4 a = *(const float4*)(x + i);
    float4 b = *(const float4*)(x + i + 4);
    short8 v;
    v[0] = (short)f2bf(a.x); v[1] = (short)f2bf(a.y);
    v[2] = (short)f2bf(a.z); v[3] = (short)f2bf(a.w);
    v[4] = (short)f2bf(b.x); v[5] = (short)f2bf(b.y);
    v[6] = (short)f2bf(b.z); v[7] = (short)f2bf(b.w);
    *(short8*)(xb + i) = v;
}

__global__ __launch_bounds__(256) void convert_w(
    const float* __restrict__ w0, const float* __restrict__ w1,
    const float* __restrict__ w2, const float* __restrict__ w3,
    const float* __restrict__ w4, unsigned short* __restrict__ wb)
{
    const float* W = blockIdx.y == 0 ? w0 : blockIdx.y == 1 ? w1 :
                     blockIdx.y == 2 ? w2 : blockIdx.y == 3 ? w3 : w4;
    int i = (blockIdx.x * 256 + threadIdx.x) * 8;              // grid (8, 5)
    float4 a = *(const float4*)(W + i);
    float4 b = *(const float4*)(W + i + 4);
    short8 v;
    v[0] = (short)f2bf(a.x); v[1] = (short)f2bf(a.y);
    v[2] = (short)f2bf(a.z); v[3] = (short)f2bf(a.w);
    v[4] = (short)f2bf(b.x); v[5] = (short)f2bf(b.y);
    v[6] = (short)f2bf(b.z); v[7] = (short)f2bf(b.w);
    *(short8*)(wb + (size_t)blockIdx.y * DIM * DIM + i) = v;
}

// ---- CSR build ------------------------------------------------------------
__global__ __launch_bounds__(256) void hist_kernel(
    const int* __restrict__ ei, int* __restrict__ deg)
{
    int e = blockIdx.x * 256 + threadIdx.x;                    // grid 2500
    atomicAdd(&deg[ei[N_EDGES + e]], 1);
}

__global__ __launch_bounds__(256) void scan1(
    const int* __restrict__ deg, int* __restrict__ off, int* __restrict__ bsum)
{
    __shared__ int s[256];
    int tid = threadIdx.x;
    int i = blockIdx.x * 256 + tid;                            // grid 196
    int v = (i < N_NODES) ? deg[i] : 0;
    s[tid] = v;
    __syncthreads();
#pragma unroll
    for (int d = 1; d < 256; d <<= 1) {
        int t = (tid >= d) ? s[tid - d] : 0;
        __syncthreads();
        s[tid] += t;
        __syncthreads();
    }
    if (i < N_NODES) off[i] = s[tid] - v;      // local exclusive scan
    if (tid == 255) bsum[blockIdx.x] = s[tid]; // block total
}

__global__ __launch_bounds__(256) void scan2(int* __restrict__ bsum)
{
    __shared__ int s[256];
    int tid = threadIdx.x;
    int v = (tid < 196) ? bsum[tid] : 0;
    s[tid] = v;
    __syncthreads();
#pragma unroll
    for (int d = 1; d < 256; d <<= 1) {
        int t = (tid >= d) ? s[tid - d] : 0;
        __syncthreads();
        s[tid] += t;
        __syncthreads();
    }
    if (tid < 196) bsum[tid] = s[tid] - v;     // exclusive block offsets
}

__global__ __launch_bounds__(256) void scan3(
    int* __restrict__ off, const int* __restrict__ bsum, int* __restrict__ cursor)
{
    int i = blockIdx.x * 256 + threadIdx.x;                    // grid 196
    if (i < N_NODES) {
        int o = off[i] + bsum[blockIdx.x];
        off[i] = o;
        cursor[i] = o;
    }
    if (i == 0) off[N_NODES] = N_EDGES;
}

__global__ __launch_bounds__(256) void pos_kernel(
    const int* __restrict__ ei, int* __restrict__ cursor,
    int* __restrict__ pos, int* __restrict__ srcp)
{
    int e = blockIdx.x * 256 + threadIdx.x;                    // grid 2500
    int d = ei[N_EDGES + e];
    int s = ei[e];
    int p = atomicAdd(&cursor[d], 1);
    pos[e] = p;
    srcp[p] = s;
}

// ---- node GEMMs from pre-converted bf16 (A,B,D,E) -------------------------
__global__ __launch_bounds__(256) void node_gemm_bf(
    const unsigned short* __restrict__ xb, const unsigned short* __restrict__ wb,
    const float* __restrict__ b0, const float* __restrict__ b1,
    const float* __restrict__ b2, const float* __restrict__ b3,
    float* __restrict__ o0, float* __restrict__ o1,
    float* __restrict__ o2, float* __restrict__ o3)
{
    __shared__ unsigned short Xs[64 * LDP];
    __shared__ unsigned short Ws[128 * LDP];
    const int tid  = threadIdx.x;
    const int mblk = blockIdx.x * 64;
    const int mid  = blockIdx.y;
    const int widx = (mid < 2) ? mid : mid + 1;    // A,B -> wb[0],wb[1]; D,E -> wb[3],wb[4]
    const unsigned short* Wm = wb + (size_t)widx * DIM * DIM;
    const float* B = mid == 0 ? b0 : mid == 1 ? b1 : mid == 2 ? b2 : b3;
    float*       O = mid == 0 ? o0 : mid == 1 ? o1 : mid == 2 ? o2 : o3;

#pragma unroll
    for (int i = 0; i < 4; ++i) {                   // X tile: 1024 short8 slots
        int slot = tid + i * 256;
        int row = slot >> 4, c8 = (slot & 15) << 3;
        int rg = mblk + row;
        short8 v = (short8)(0);
        if (rg < N_NODES) v = *(const short8*)(xb + (size_t)rg * DIM + c8);
        *(short8*)&Xs[row * LDP + c8] = v;
    }
#pragma unroll
    for (int i = 0; i < 8; ++i) {                   // W: 2048 short8 slots
        int slot = tid + i * 256;
        int row = slot >> 4, c8 = (slot & 15) << 3;
        *(short8*)&Ws[row * LDP + c8] = *(const short8*)(Wm + row * DIM + c8);
    }
    __syncthreads();

    const int wave = tid >> 6, lane = tid & 63;
    const int q = lane >> 4, r = lane & 15;
    floatx4 acc[8];
#pragma unroll
    for (int i = 0; i < 8; ++i) acc[i] = (floatx4)(0.f);
    const int arow = wave * 16 + r;
#pragma unroll
    for (int kk = 0; kk < 4; ++kk) {
        short8 a = *(const short8*)&Xs[arow * LDP + kk * 32 + q * 8];
#pragma unroll
        for (int nt = 0; nt < 8; ++nt) {
            short8 b = *(const short8*)&Ws[(nt * 16 + r) * LDP + kk * 32 + q * 8];
            acc[nt] = __builtin_amdgcn_mfma_f32_16x16x32_bf16(a, b, acc[nt], 0, 0, 0);
        }
    }
#pragma unroll
    for (int nt = 0; nt < 8; ++nt) {
        int col = nt * 16 + r;
        float bv = B[col];
#pragma unroll
        for (int reg = 0; reg < 4; ++reg) {
            int rg = mblk + wave * 16 + q * 4 + reg;
            if (rg < N_NODES) O[(size_t)rg * DIM + col] = acc[nt][reg] + bv;
        }
    }
}

// ---- fused edge kernel, no atomics: writes dst-permuted sigma -------------
__global__ __launch_bounds__(256) void edge_kernel_v2(
    const float* __restrict__ e,
    const unsigned short* __restrict__ wb, const float* __restrict__ Cb,
    const int* __restrict__ ei,
    const float* __restrict__ Dx, const float* __restrict__ Ex,
    const int* __restrict__ pos,
    const float* __restrict__ g,  const float* __restrict__ bt,
    const float* __restrict__ mn, const float* __restrict__ vr,
    float* __restrict__ sigp, float* __restrict__ e_out)
{
    __shared__ unsigned short Es[64 * LDP];
    __shared__ unsigned short Ws[128 * LDP];
    __shared__ int srcS[64], dstS[64], posS[64];
    const int tid  = threadIdx.x;
    const int mblk = blockIdx.x * 64;

    if (tid < 64) {
        srcS[tid] = ei[mblk + tid];            // edge_index[0] = source
        dstS[tid] = ei[N_EDGES + mblk + tid];  // edge_index[1] = target
        posS[tid] = pos[mblk + tid];
    }
#pragma unroll
    for (int i = 0; i < 8; ++i) {
        int slot = tid + i * 256;
        int row = slot >> 5, c4 = (slot & 31) << 2;
        float4 v = *(const float4*)(e + (size_t)(mblk + row) * DIM + c4);
        unsigned short* p = &Es[row * LDP + c4];
        p[0] = f2bf(v.x); p[1] = f2bf(v.y); p[2] = f2bf(v.z); p[3] = f2bf(v.w);
    }
    const unsigned short* Wm = wb + (size_t)2 * DIM * DIM;     // Cw
#pragma unroll
    for (int i = 0; i < 8; ++i) {
        int slot = tid + i * 256;
        int row = slot >> 4, c8 = (slot & 15) << 3;
        *(short8*)&Ws[row * LDP + c8] = *(const short8*)(Wm + row * DIM + c8);
    }
    __syncthreads();

    const int wave = tid >> 6, lane = tid & 63;
    const int q = lane >> 4, r = lane & 15;
    floatx4 acc[8];
#pragma unroll
    for (int i = 0; i < 8; ++i) acc[i] = (floatx4)(0.f);
    const int arow = wave * 16 + r;
#pragma unroll
    for (int kk = 0; kk < 4; ++kk) {
        short8 a = *(const short8*)&Es[arow * LDP + kk * 32 + q * 8];
#pragma unroll
        for (int nt = 0; nt < 8; ++nt) {
            short8 b = *(const short8*)&Ws[(nt * 16 + r) * LDP + kk * 32 + q * 8];
            acc[nt] = __builtin_amdgcn_mfma_f32_16x16x32_bf16(a, b, acc[nt], 0, 0, 0);
        }
    }

#pragma unroll
    for (int nt = 0; nt < 8; ++nt) {
        int col = nt * 16 + r;
        float cb = Cb[col];
        float sc = g[col] * rsqrtf(vr[col] + 1e-5f);
        float sh = bt[col] - mn[col] * sc;
#pragma unroll
        for (int reg = 0; reg < 4; ++reg) {
            int rl = wave * 16 + q * 4 + reg;
            int rg = mblk + rl;
            int dd = dstS[rl], ss = srcS[rl];
            float eij = acc[nt][reg] + cb
                      + Dx[(size_t)dd * DIM + col] + Ex[(size_t)ss * DIM + col];
            float sg = 1.f / (1.f + __expf(-eij));
            sigp[(size_t)posS[rl] * DIM + col] = sg;
            float bn = eij * sc + sh;
            e_out[(size_t)rg * DIM + col] = bf2f(Es[rl * LDP + col]) + (bn > 0.f ? bn : 0.f);
        }
    }
}

// ---- node aggregation + BN + relu + residual (replaces atomics+node_final)
__global__ __launch_bounds__(256) void node_aggr(
    const float* __restrict__ x,  const float* __restrict__ Ax,
    const float* __restrict__ Bx, const float* __restrict__ sigp,
    const int* __restrict__ srcp, const int* __restrict__ off,
    const float* __restrict__ g,  const float* __restrict__ bt,
    const float* __restrict__ mn, const float* __restrict__ vr,
    float* __restrict__ x_out)
{
    int node = blockIdx.x * 4 + (threadIdx.x >> 6);            // grid 12500
    int lane = threadIdx.x & 63;
    int c0 = lane * 2;
    int lo = off[node], hi = off[node + 1];
    float n0 = 0.f, n1 = 0.f, d0 = 0.f, d1 = 0.f;
    for (int k = lo; k < hi; ++k) {
        float2 sg = *(const float2*)(sigp + (size_t)k * DIM + c0);
        int s = srcp[k];
        float2 bx = *(const float2*)(Bx + (size_t)s * DIM + c0);
        n0 += sg.x * bx.x; n1 += sg.y * bx.y;
        d0 += sg.x;        d1 += sg.y;
    }
    float2 gv  = *(const float2*)(g + c0);
    float2 btv = *(const float2*)(bt + c0);
    float2 mnv = *(const float2*)(mn + c0);
    float2 vrv = *(const float2*)(vr + c0);
    float2 av  = *(const float2*)(Ax + (size_t)node * DIM + c0);
    float2 xv  = *(const float2*)(x  + (size_t)node * DIM + c0);
    float sc0 = gv.x * rsqrtf(vrv.x + 1e-5f);
    float sc1 = gv.y * rsqrtf(vrv.y + 1e-5f);
    float v0 = av.x + n0 / (d0 + 1e-6f);
    float v1 = av.y + n1 / (d1 + 1e-6f);
    float bn0 = (v0 - mnv.x) * sc0 + btv.x;
    float bn1 = (v1 - mnv.y) * sc1 + btv.y;
    float2 o;
    o.x = xv.x + (bn0 > 0.f ? bn0 : 0.f);
    o.y = xv.y + (bn1 > 0.f ? bn1 : 0.f);
    *(float2*)(x_out + (size_t)node * DIM + c0) = o;
}

// ===========================================================================
// FALLBACK PATH (previous verified pipeline) — used only if ws_size too small
// ===========================================================================
__global__ __launch_bounds__(256) void node_gemm_old(
    const float* __restrict__ x,
    const float* __restrict__ w0, const float* __restrict__ b0,
    const float* __restrict__ w1, const float* __restrict__ b1,
    const float* __restrict__ w2, const float* __restrict__ b2,
    const float* __restrict__ w3, const float* __restrict__ b3,
    float* __restrict__ o0, float* __restrict__ o1,
    float* __restrict__ o2, float* __restrict__ o3)
{
    __shared__ unsigned short Xs[64 * LDP];
    __shared__ unsigned short Ws[128 * LDP];
    const int tid  = threadIdx.x;
    const int mblk = blockIdx.x * 64;
    const int mid  = blockIdx.y;
    const float* W = mid == 0 ? w0 : mid == 1 ? w1 : mid == 2 ? w2 : w3;
    const float* B = mid == 0 ? b0 : mid == 1 ? b1 : mid == 2 ? b2 : b3;
    float*       O = mid == 0 ? o0 : mid == 1 ? o1 : mid == 2 ? o2 : o3;

#pragma unroll
    for (int i = 0; i < 8; ++i) {
        int slot = tid + i * 256;
        int row = slot >> 5, c4 = (slot & 31) << 2;
        int rg = mblk + row;
        float4 v = make_float4(0.f, 0.f, 0.f, 0.f);
        if (rg < N_NODES) v = *(const float4*)(x + (size_t)rg * DIM + c4);
        unsigned short* p = &Xs[row * LDP + c4];
        p[0] = f2bf(v.x); p[1] = f2bf(v.y); p[2] = f2bf(v.z); p[3] = f2bf(v.w);
    }
#pragma unroll
    for (int i = 0; i < 16; ++i) {
        int slot = tid + i * 256;
        int row = slot >> 5, c4 = (slot & 31) << 2;
        float4 v = *(const float4*)(W + row * DIM + c4);
        unsigned short* p = &Ws[row * LDP + c4];
        p[0] = f2bf(v.x); p[1] = f2bf(v.y); p[2] = f2bf(v.z); p[3] = f2bf(v.w);
    }
    __syncthreads();

    const int wave = tid >> 6, lane = tid & 63;
    const int q = lane >> 4, r = lane & 15;
    floatx4 acc[8];
#pragma unroll
    for (int i = 0; i < 8; ++i) acc[i] = (floatx4)(0.f);
    const int arow = wave * 16 + r;
#pragma unroll
    for (int kk = 0; kk < 4; ++kk) {
        short8 a = *(const short8*)&Xs[arow * LDP + kk * 32 + q * 8];
#pragma unroll
        for (int nt = 0; nt < 8; ++nt) {
            short8 b = *(const short8*)&Ws[(nt * 16 + r) * LDP + kk * 32 + q * 8];
            acc[nt] = __builtin_amdgcn_mfma_f32_16x16x32_bf16(a, b, acc[nt], 0, 0, 0);
        }
    }
#pragma unroll
    for (int nt = 0; nt < 8; ++nt) {
        int col = nt * 16 + r;
        float bv = B[col];
#pragma unroll
        for (int reg = 0; reg < 4; ++reg) {
            int rg = mblk + wave * 16 + q * 4 + reg;
            if (rg < N_NODES) O[(size_t)rg * DIM + col] = acc[nt][reg] + bv;
        }
    }
}

__global__ __launch_bounds__(256) void edge_kernel_atomic(
    const float* __restrict__ e,
    const float* __restrict__ Cw, const float* __restrict__ Cb,
    const int* __restrict__ ei,
    const float* __restrict__ Dx, const float* __restrict__ Ex,
    const float* __restrict__ Bx,
    const float* __restrict__ g,  const float* __restrict__ bt,
    const float* __restrict__ mn, const float* __restrict__ vr,
    float* __restrict__ num, float* __restrict__ den,
    float* __restrict__ e_out)
{
    __shared__ unsigned short Es[64 * LDP];
    __shared__ unsigned short Ws[128 * LDP];
    __shared__ int srcS[64], dstS[64];
    const int tid  = threadIdx.x;
    const int mblk = blockIdx.x * 64;

    if (tid < 64) {
        srcS[tid] = ei[mblk + tid];
        dstS[tid] = ei[N_EDGES + mblk + tid];
    }
#pragma unroll
    for (int i = 0; i < 8; ++i) {
        int slot = tid + i * 256;
        int row = slot >> 5, c4 = (slot & 31) << 2;
        float4 v = *(const float4*)(e + (size_t)(mblk + row) * DIM + c4);
        unsigned short* p = &Es[row * LDP + c4];
        p[0] = f2bf(v.x); p[1] = f2bf(v.y); p[2] = f2bf(v.z); p[3] = f2bf(v.w);
    }
#pragma unroll
    for (int i = 0; i < 16; ++i) {
        int slot = tid + i * 256;
        int row = slot >> 5, c4 = (slot & 31) << 2;
        float4 v = *(const float4*)(Cw + row * DIM + c4);
        unsigned short* p = &Ws[row * LDP + c4];
        p[0] = f2bf(v.x); p[1] = f2bf(v.y); p[2] = f2bf(v.z); p[3] = f2bf(v.w);
    }
    __syncthreads();

    const int wave = tid >> 6, lane = tid & 63;
    const int q = lane >> 4, r = lane & 15;
    floatx4 acc[8];
#pragma unroll
    for (int i = 0; i < 8; ++i) acc[i] = (floatx4)(0.f);
    const int arow = wave * 16 + r;
#pragma unroll
    for (int kk = 0; kk < 4; ++kk) {
        short8 a = *(const short8*)&Es[arow * LDP + kk * 32 + q * 8];
#pragma unroll
        for (int nt = 0; nt < 8; ++nt) {
            short8 b = *(const short8*)&Ws[(nt * 16 + r) * LDP + kk * 32 + q * 8];
            acc[nt] = __builtin_amdgcn_mfma_f32_16x16x32_bf16(a, b, acc[nt], 0, 0, 0);
        }
    }
#pragma unroll
    for (int nt = 0; nt < 8; ++nt) {
        int col = nt * 16 + r;
        float cb = Cb[col];
        float sc = g[col] * rsqrtf(vr[col] + 1e-5f);
        float sh = bt[col] - mn[col] * sc;
#pragma unroll
        for (int reg = 0; reg < 4; ++reg) {
            int rl = wave * 16 + q * 4 + reg;
            int rg = mblk + rl;
            int dd = dstS[rl], ss = srcS[rl];
            float eij = acc[nt][reg] + cb
                      + Dx[(size_t)dd * DIM + col] + Ex[(size_t)ss * DIM + col];
            float sg = 1.f / (1.f + __expf(-eij));
            atomicAdd(&num[(size_t)dd * DIM + col], sg * Bx[(size_t)ss * DIM + col]);
            atomicAdd(&den[(size_t)dd * DIM + col], sg);
            float bn = eij * sc + sh;
            e_out[(size_t)rg * DIM + col] = bf2f(Es[rl * LDP + col]) + (bn > 0.f ? bn : 0.f);
        }
    }
}

__global__ __launch_bounds__(256) void node_final(
    const float* __restrict__ x,  const float* __restrict__ Ax,
    const float* __restrict__ num, const float* __restrict__ den,
    const float* __restrict__ g,  const float* __restrict__ bt,
    const float* __restrict__ mn, const float* __restrict__ vr,
    float* __restrict__ x_out)
{
    int idx = (blockIdx.x * 256 + threadIdx.x) * 4;
    float4 a  = *(const float4*)(Ax + idx);
    float4 nm = *(const float4*)(num + idx);
    float4 dn = *(const float4*)(den + idx);
    float4 xv = *(const float4*)(x + idx);
    int col = idx & (DIM - 1);
    float av[4] = {a.x, a.y, a.z, a.w};
    float nv[4] = {nm.x, nm.y, nm.z, nm.w};
    float dv[4] = {dn.x, dn.y, dn.z, dn.w};
    float xs[4] = {xv.x, xv.y, xv.z, xv.w};
    float ov[4];
#pragma unroll
    for (int j = 0; j < 4; ++j) {
        float sc = g[col + j] * rsqrtf(vr[col + j] + 1e-5f);
        float sh = bt[col + j] - mn[col + j] * sc;
        float v = av[j] + nv[j] / (dv[j] + 1e-6f);
        float bn = v * sc + sh;
        ov[j] = xs[j] + (bn > 0.f ? bn : 0.f);
    }
    *(float4*)(x_out + idx) = make_float4(ov[0], ov[1], ov[2], ov[3]);
}

// ===========================================================================
extern "C" void kernel_launch(void* const* d_in, const int* in_sizes, int n_in,
                              void* d_out, int out_size, void* d_ws, size_t ws_size,
                              hipStream_t stream) {
    const float* x  = (const float*)d_in[0];
    const float* e  = (const float*)d_in[1];
    const float* Aw = (const float*)d_in[2];  const float* Ab = (const float*)d_in[3];
    const float* Bw = (const float*)d_in[4];  const float* Bb = (const float*)d_in[5];
    const float* Cw = (const float*)d_in[6];  const float* Cb = (const float*)d_in[7];
    const float* Dw = (const float*)d_in[8];  const float* Db = (const float*)d_in[9];
    const float* Ew = (const float*)d_in[10]; const float* Eb = (const float*)d_in[11];
    const float* gx = (const float*)d_in[12]; const float* btx = (const float*)d_in[13];
    const float* mnx = (const float*)d_in[14]; const float* vrx = (const float*)d_in[15];
    const float* ge = (const float*)d_in[16]; const float* bte = (const float*)d_in[17];
    const float* mne = (const float*)d_in[18]; const float* vre = (const float*)d_in[19];
    const int*   ei = (const int*)d_in[20];

    const size_t NF = (size_t)N_NODES * DIM;   // 6.4M floats
    const size_t EF = (size_t)N_EDGES * DIM;   // 81.92M floats

    float* x_out = (float*)d_out;
    float* e_out = x_out + NF;

    // ---- new-path workspace layout (256B-aligned slabs) ----
    char* base = (char*)d_ws;
    size_t need = 0;
    #define WS_ALLOC(ty, name, bytes) \
        ty* name = (ty*)(base + need); need = (need + (size_t)(bytes) + 255) & ~(size_t)255;
    WS_ALLOC(float, Ax, NF * 4)
    WS_ALLOC(float, Bx, NF * 4)
    WS_ALLOC(float, Dx, NF * 4)
    WS_ALLOC(float, Ex, NF * 4)
    WS_ALLOC(float, sigp, EF * 4)
    WS_ALLOC(unsigned short, xb, NF * 2)
    WS_ALLOC(unsigned short, wb, (size_t)5 * DIM * DIM * 2)
    WS_ALLOC(int, deg, N_NODES * 4)
    WS_ALLOC(int, offp, (N_NODES + 1) * 4)
    WS_ALLOC(int, cursor, N_NODES * 4)
    WS_ALLOC(int, bsum, 256 * 4)
    WS_ALLOC(int, pos, N_EDGES * 4)
    WS_ALLOC(int, srcp, N_EDGES * 4)
    #undef WS_ALLOC

    if (ws_size >= need) {
        // ---------------- new path: CSR gather aggregation, no f32 atomics
        hipMemsetAsync(deg, 0, (size_t)N_NODES * 4, stream);
        convert_x<<<3125, 256, 0, stream>>>(x, xb);
        convert_w<<<dim3(8, 5), 256, 0, stream>>>(Aw, Bw, Cw, Dw, Ew, wb);

        hist_kernel<<<N_EDGES / 256, 256, 0, stream>>>(ei, deg);
        scan1<<<196, 256, 0, stream>>>(deg, offp, bsum);
        scan2<<<1, 256, 0, stream>>>(bsum);
        scan3<<<196, 256, 0, stream>>>(offp, bsum, cursor);
        pos_kernel<<<N_EDGES / 256, 256, 0, stream>>>(ei, cursor, pos, srcp);

        dim3 g1((N_NODES + 63) / 64, 4);
        node_gemm_bf<<<g1, 256, 0, stream>>>(xb, wb, Ab, Bb, Db, Eb, Ax, Bx, Dx, Ex);

        edge_kernel_v2<<<N_EDGES / 64, 256, 0, stream>>>(e, wb, Cb, ei, Dx, Ex, pos,
                                                         ge, bte, mne, vre, sigp, e_out);

        node_aggr<<<N_NODES / 4, 256, 0, stream>>>(x, Ax, Bx, sigp, srcp, offp,
                                                   gx, btx, mnx, vrx, x_out);
    } else {
        // ---------------- fallback: previous verified atomic pipeline
        float* ws  = (float*)d_ws;
        float* fAx  = ws;
        float* fBx  = ws + NF;
        float* fDx  = ws + 2 * NF;
        float* fEx  = ws + 3 * NF;
        float* num = ws + 4 * NF;
        float* den = ws + 5 * NF;

        hipMemsetAsync(num, 0, 2 * NF * sizeof(float), stream);

        dim3 g1((N_NODES + 63) / 64, 4);
        node_gemm_old<<<g1, 256, 0, stream>>>(x, Aw, Ab, Bw, Bb, Dw, Db, Ew, Eb,
                                              fAx, fBx, fDx, fEx);
        edge_kernel_atomic<<<N_EDGES / 64, 256, 0, stream>>>(e, Cw, Cb, ei, fDx, fEx, fBx,
                                                             ge, bte, mne, vre, num, den, e_out);
        node_final<<<(int)(NF / 4 / 256), 256, 0, stream>>>(x, fAx, num, den,
                                                            gx, btx, mnx, vrx, x_out);
    }
}